// Round 1
// 580.673 us; speedup vs baseline: 1.2617x; 1.2617x over previous
//
#include <hip/hip_runtime.h>

// Trilinear sparse-voxel upsampling, SCALE=2, R=128, C=32.
// fine = 2*c + o (o in {0,1}^3) => per-axis neighbors {c-1+o (w=0.25+0.5o), c+o (w=0.75-0.5o)}.
// Wave-per-coarse-voxel: the 8 children share a 27-voxel neighborhood.
//   Phase 1: lanes 0-26 look up the 27 neighbors once (1 load instr, ballot -> valid mask)
//   Phase 2: cooperative staging of valid feat rows into LDS (4 rounds x 8 rows x 8 float4)
//   Phase 3: each lane (child, part) combines its 8 corners from LDS, skipping invalid ones.

#define R 128
#define TABLE_ELEMS (R * R * R)

typedef float f32x4 __attribute__((ext_vector_type(4)));

__global__ void build_table_kernel(const int* __restrict__ coarse,
                                   int* __restrict__ table, int n) {
    int i = blockIdx.x * blockDim.x + threadIdx.x;
    if (i >= n) return;
    int x = coarse[i * 3 + 0];
    int y = coarse[i * 3 + 1];
    int z = coarse[i * 3 + 2];
    // numpy last-write-wins with increasing values == max row index
    atomicMax(&table[(x * R + y) * R + z], i);
}

__global__ void __launch_bounds__(256)
upsample_kernel(const f32x4* __restrict__ feat4,   // [n_in, 8] f32x4 == [n_in,32] f32
                const int* __restrict__ coarse,    // [n_in, 3]
                const int* __restrict__ table,     // [128^3]
                f32x4* __restrict__ out4,          // [8*n_in, 8] f32x4
                int n_in) {
    __shared__ f32x4 sm[4][27 * 8];                // 13824 B: 27 neighbor rows per wave

    int wib  = threadIdx.x >> 6;                   // wave within block
    int lane = threadIdx.x & 63;
    int vi   = blockIdx.x * 4 + wib;               // one coarse voxel per wave
    vi = __builtin_amdgcn_readfirstlane(vi);       // force SGPR (wave-uniform)
    if (vi >= n_in) return;

    int cx = coarse[vi * 3 + 0];
    int cy = coarse[vi * 3 + 1];
    int cz = coarse[vi * 3 + 2];

    // ---- Phase 1: 27-neighborhood hash lookup, one neighbor per lane ----
    int myidx = -1;
    if (lane < 27) {
        int dx  = lane / 9;
        int rem = lane - dx * 9;
        int dy  = rem / 3;
        int dz  = rem - dy * 3;
        int x = cx + dx - 1, y = cy + dy - 1, z = cz + dz - 1;
        if ((unsigned)x < (unsigned)R && (unsigned)y < (unsigned)R &&
            (unsigned)z < (unsigned)R)
            myidx = table[(x * R + y) * R + z];
    }
    unsigned long long vmask = __ballot(myidx >= 0);   // wave-uniform 27-bit validity

    // ---- Phase 2: stage valid neighbor rows into LDS ----
    int g = lane >> 3;                             // row-slot / child id
    int part = lane & 7;                           // which f32x4 of the 32-ch row
    f32x4* smw = sm[wib];
#pragma unroll
    for (int r = 0; r < 4; ++r) {
        int nb  = r * 8 + g;                       // 0..31; 27..31 are always invalid
        int idx = __shfl(myidx, nb);               // lanes >=27 hold -1
        if (idx >= 0)
            smw[nb * 8 + part] = feat4[(size_t)idx * 8 + part];
    }
    // wave-local producer->consumer: drain our own ds_writes before reading
    asm volatile("s_waitcnt lgkmcnt(0)" ::: "memory");
    __builtin_amdgcn_sched_barrier(0);

    // ---- Phase 3: child (g) x part: combine 8 corners from LDS ----
    int ox = (g >> 2) & 1, oy = (g >> 1) & 1, oz = g & 1;
    float wx0 = 0.25f + 0.5f * (float)ox, wx1 = 0.75f - 0.5f * (float)ox;
    float wy0 = 0.25f + 0.5f * (float)oy, wy1 = 0.75f - 0.5f * (float)oy;
    float wz0 = 0.25f + 0.5f * (float)oz, wz1 = 0.75f - 0.5f * (float)oz;

    f32x4 acc = (f32x4)(0.f);
#pragma unroll
    for (int k = 0; k < 8; ++k) {
        int kx = (k >> 2) & 1, ky = (k >> 1) & 1, kz = k & 1;
        int nb = (ox + kx) * 9 + (oy + ky) * 3 + (oz + kz);
        if ((vmask >> nb) & 1ull) {
            float w = (kx ? wx1 : wx0) * (ky ? wy1 : wy0) * (kz ? wz1 : wz0);
            f32x4 f = smw[nb * 8 + part];
            acc += w * f;
        }
    }

    // out row m = vi*8 + child; element m*8 + part == vi*64 + lane (1 KB/wave, coalesced)
    __builtin_nontemporal_store(acc, &out4[(size_t)vi * 64 + lane]);
}

extern "C" void kernel_launch(void* const* d_in, const int* in_sizes, int n_in_arrs,
                              void* d_out, int out_size, void* d_ws, size_t ws_size,
                              hipStream_t stream) {
    const float* feat = (const float*)d_in[0];
    const int* coarse = (const int*)d_in[1];
    // d_in[2] (fine_coords) is derivable from coarse_coords -- not read.

    int n_in = in_sizes[1] / 3;            // 400000
    int* table = (int*)d_ws;               // 8 MB scratch

    hipMemsetAsync(table, 0xFF, (size_t)TABLE_ELEMS * sizeof(int), stream);

    build_table_kernel<<<(n_in + 255) / 256, 256, 0, stream>>>(coarse, table, n_in);

    int nblocks = (n_in + 3) / 4;          // one wave (64 threads) per coarse voxel
    upsample_kernel<<<nblocks, 256, 0, stream>>>(
        (const f32x4*)feat, coarse, table, (f32x4*)d_out, n_in);
}